// Round 1
// baseline (974.403 us; speedup 1.0000x reference)
//
#include <hip/hip_runtime.h>
#include <math.h>

// MutualInformationLoss on MI355X.
// pred, target: [4, 1, 96,96,96] fp32 in [0,1). Output: scalar fp32 = -mean_b MI_b.
//
// Stage 1: per (batch, chunk) block builds a partial 23x23 joint histogram in
//          LDS via fp32 ds-atomics, using a 7-bin Gaussian window (truncation
//          error < 1e-10 of mass; exp(-968*(3.5/22*22... )^2)=e^-24.5).
// Stage 2: one block reduces the 128 chunk partials per batch in fp64,
//          derives marginals as row/col sums, computes MI in fp64.

#define NBINS   23
#define NCELLS  529           // 23*23
#define NBATCH  4
#define NVOX    884736        // 96^3
#define CHUNKS  128
#define VPC     (NVOX / CHUNKS)   // 6912 voxels per block
#define THREADS 256
#define WIN     7

__global__ __launch_bounds__(THREADS)
void mi_pab_partial(const float* __restrict__ pred,
                    const float* __restrict__ targ,
                    float* __restrict__ partial)   // [NBATCH][NCELLS][CHUNKS]
{
    __shared__ float s_pab[NCELLS];
    const int chunk = blockIdx.x;
    const int b     = blockIdx.y;

    for (int c = threadIdx.x; c < NCELLS; c += THREADS) s_pab[c] = 0.0f;
    __syncthreads();

    const float* __restrict__ px = pred + (size_t)b * NVOX + (size_t)chunk * VPC;
    const float* __restrict__ py = targ + (size_t)b * NVOX + (size_t)chunk * VPC;

    const float BINW = (float)(1.0 / 22.0);
    const float PT   = 968.0f;   // 1/(2*sigma^2), sigma = (1/22)*0.5

    for (int v = threadIdx.x; v < VPC; v += THREADS) {
        float x = px[v]; x = fminf(fmaxf(x, 0.0f), 1.0f);
        float y = py[v]; y = fminf(fmaxf(y, 0.0f), 1.0f);

        // nearest bin, then a fixed 7-wide window clamped inside [0,22].
        int ka = (int)floorf(fmaf(x, 22.0f, 0.5f));
        int kb = (int)floorf(fmaf(y, 22.0f, 0.5f));
        int ia = ka - 3; ia = ia < 0 ? 0 : (ia > 16 ? 16 : ia);
        int ib = kb - 3; ib = ib < 0 ? 0 : (ib > 16 ? 16 : ib);

        float wa[WIN], wb[WIN];
        float sa = 0.0f, sb = 0.0f;
        #pragma unroll
        for (int t = 0; t < WIN; ++t) {
            float da = x - (float)(ia + t) * BINW;
            float wav = expf(-PT * da * da);
            wa[t] = wav; sa += wav;
            float db = y - (float)(ib + t) * BINW;
            float wbv = expf(-PT * db * db);
            wb[t] = wbv; sb += wbv;
        }
        float scale = 1.0f / (sa * sb);

        const int base = ia * NBINS + ib;
        #pragma unroll
        for (int ta = 0; ta < WIN; ++ta) {
            float fa = wa[ta] * scale;
            int rb = base + ta * NBINS;
            #pragma unroll
            for (int tb = 0; tb < WIN; ++tb) {
                atomicAdd(&s_pab[rb + tb], fa * wb[tb]);
            }
        }
    }
    __syncthreads();

    // cell-major layout so stage 2 reads contiguous [CHUNKS] runs per cell
    for (int c = threadIdx.x; c < NCELLS; c += THREADS)
        partial[((size_t)b * NCELLS + c) * CHUNKS + chunk] = s_pab[c];
}

__global__ __launch_bounds__(THREADS)
void mi_finalize(const float* __restrict__ partial, float* __restrict__ out)
{
    __shared__ double s_pab[NCELLS];
    __shared__ double s_pa[NBINS];
    __shared__ double s_pb[NBINS];
    __shared__ double s_red[4];

    double total = 0.0;   // only thread 0's copy matters

    for (int b = 0; b < NBATCH; ++b) {
        // fp64 cross-chunk reduction
        for (int c = threadIdx.x; c < NCELLS; c += THREADS) {
            const float4* p = (const float4*)(partial + ((size_t)b * NCELLS + c) * CHUNKS);
            double s = 0.0;
            #pragma unroll 4
            for (int k = 0; k < CHUNKS / 4; ++k) {
                float4 q = p[k];
                s += (double)q.x + (double)q.y + (double)q.z + (double)q.w;
            }
            s_pab[c] = s * (1.0 / (double)NVOX);
        }
        __syncthreads();

        // marginals as row/col sums (differs from reference mean(w) by ~1e-7 rel)
        if (threadIdx.x < NBINS) {
            const int i = threadIdx.x;
            double r = 0.0, cl = 0.0;
            for (int j = 0; j < NBINS; ++j) {
                r  += s_pab[i * NBINS + j];
                cl += s_pab[j * NBINS + i];
            }
            s_pa[i] = r; s_pb[i] = cl;
        }
        __syncthreads();

        double t = 0.0;
        for (int c = threadIdx.x; c < NCELLS; c += THREADS) {
            double pab  = s_pab[c];
            double papb = s_pa[c / NBINS] * s_pb[c % NBINS];
            t += pab * log((pab + 1e-7) / (papb + 1e-7) + 1e-7);
        }
        #pragma unroll
        for (int off = 32; off > 0; off >>= 1)
            t += __shfl_down(t, off, 64);
        if ((threadIdx.x & 63) == 0) s_red[threadIdx.x >> 6] = t;
        __syncthreads();
        if (threadIdx.x == 0)
            total += s_red[0] + s_red[1] + s_red[2] + s_red[3];
        __syncthreads();
    }

    if (threadIdx.x == 0) out[0] = (float)(-total * 0.25);
}

extern "C" void kernel_launch(void* const* d_in, const int* in_sizes, int n_in,
                              void* d_out, int out_size, void* d_ws, size_t ws_size,
                              hipStream_t stream)
{
    const float* pred = (const float*)d_in[0];
    const float* targ = (const float*)d_in[1];
    float* out = (float*)d_out;
    float* partial = (float*)d_ws;   // NBATCH*NCELLS*CHUNKS floats = ~1.06 MB

    dim3 grid(CHUNKS, NBATCH);
    mi_pab_partial<<<grid, THREADS, 0, stream>>>(pred, targ, partial);
    mi_finalize<<<1, THREADS, 0, stream>>>(partial, out);
}

// Round 2
// 619.212 us; speedup vs baseline: 1.5736x; 1.5736x over previous
//
#include <hip/hip_runtime.h>
#include <math.h>

// MutualInformationLoss on MI355X — round 2.
// Round-1 bottleneck: 49 LDS fp32 atomics/voxel, lane-serialized (~196 cyc per
// wave-instr) -> 868 us with all pipes idle. Fix: bucket voxels by nearest-bin
// pair (ka,kb); all voxels in a bucket hit the SAME 49 cells, so the outer
// product accumulates in 49 registers per thread with zero atomics.
//
//  K1 mi_scatter : append (x,y) to bucket[b][ka][kb]   (1 global atomic/voxel)
//  K2 mi_accum   : block per bucket, register-accumulate 7x7, reduce, 49
//                  global atomicAdds into pab_f32[b][529]
//  K3 mi_finalize: fp64 marginals + MI, single block
// Fallback to round-1 kernels if ws_size < ~35 MB.

#define NBINS   23
#define NCELLS  529
#define NBATCH  4
#define NVOX    884736
#define NBUCK   (NBATCH * NCELLS)     // 2116
#define CAP     2048                  // expected max bucket ~1966; overflow -> slow path
#define WIN     7
#define SCHUNKS 512
#define SVPC    (NVOX / SCHUNKS)      // 1728

#define R1CHUNKS 128
#define R1VPC    (NVOX / R1CHUNKS)

__device__ __forceinline__ void window_weights(float x, int ia, float* w, float& s)
{
    const float BINW = (float)(1.0 / 22.0);
    const float PT   = 968.0f;
    s = 0.0f;
    #pragma unroll
    for (int t = 0; t < WIN; ++t) {
        float d = x - (float)(ia + t) * BINW;
        float wv = expf(-PT * d * d);
        w[t] = wv; s += wv;
    }
}

// ---------------- K1: scatter-append ----------------
__global__ __launch_bounds__(256)
void mi_scatter(const float* __restrict__ pred,
                const float* __restrict__ targ,
                unsigned int* __restrict__ cnt,     // [NBUCK]
                float2* __restrict__ buf,           // [NBUCK][CAP]
                float* __restrict__ pab)            // [NBATCH][NCELLS] overflow target
{
    const int chunk = blockIdx.x;
    const int b     = blockIdx.y;
    const float* __restrict__ px = pred + (size_t)b * NVOX + (size_t)chunk * SVPC;
    const float* __restrict__ py = targ + (size_t)b * NVOX + (size_t)chunk * SVPC;

    for (int v = threadIdx.x; v < SVPC; v += 256) {
        float x = px[v]; x = fminf(fmaxf(x, 0.0f), 1.0f);
        float y = py[v]; y = fminf(fmaxf(y, 0.0f), 1.0f);
        int ka = (int)floorf(fmaf(x, 22.0f, 0.5f));
        int kb = (int)floorf(fmaf(y, 22.0f, 0.5f));
        int bucket = (b * NBINS + ka) * NBINS + kb;
        unsigned int pos = atomicAdd(&cnt[bucket], 1u);
        if (pos < CAP) {
            buf[(size_t)bucket * CAP + pos] = make_float2(x, y);
        } else {
            // rare overflow: contribute directly (keeps result exact for any CAP)
            int ia = ka - 3; ia = ia < 0 ? 0 : (ia > 16 ? 16 : ia);
            int ib = kb - 3; ib = ib < 0 ? 0 : (ib > 16 ? 16 : ib);
            float wa[WIN], wb[WIN], sa, sb;
            window_weights(x, ia, wa, sa);
            window_weights(y, ib, wb, sb);
            float scale = 1.0f / (sa * sb);
            #pragma unroll
            for (int ta = 0; ta < WIN; ++ta) {
                float fa = wa[ta] * scale;
                #pragma unroll
                for (int tb = 0; tb < WIN; ++tb)
                    atomicAdd(&pab[b * NCELLS + (ia + ta) * NBINS + (ib + tb)], fa * wb[tb]);
            }
        }
    }
}

// ---------------- K2: dense register accumulation per bucket ----------------
__global__ __launch_bounds__(256)
void mi_accum(const unsigned int* __restrict__ cnt,
              const float2* __restrict__ buf,
              float* __restrict__ pab)
{
    const int bucket = blockIdx.x;
    const int kb = bucket % NBINS;
    const int ka = (bucket / NBINS) % NBINS;
    const int b  = bucket / NCELLS;
    int ia = ka - 3; ia = ia < 0 ? 0 : (ia > 16 ? 16 : ia);
    int ib = kb - 3; ib = ib < 0 ? 0 : (ib > 16 ? 16 : ib);

    unsigned int n = cnt[bucket];
    if (n > CAP) n = CAP;

    float acc[WIN * WIN];
    #pragma unroll
    for (int c = 0; c < WIN * WIN; ++c) acc[c] = 0.0f;

    const float2* __restrict__ bp = buf + (size_t)bucket * CAP;
    for (unsigned int v = threadIdx.x; v < n; v += 256) {
        float2 p = bp[v];
        float wa[WIN], wb[WIN], sa, sb;
        window_weights(p.x, ia, wa, sa);
        window_weights(p.y, ib, wb, sb);
        float scale = 1.0f / (sa * sb);
        #pragma unroll
        for (int ta = 0; ta < WIN; ++ta) {
            float fa = wa[ta] * scale;
            #pragma unroll
            for (int tb = 0; tb < WIN; ++tb)
                acc[ta * WIN + tb] = fmaf(fa, wb[tb], acc[ta * WIN + tb]);
        }
    }

    __shared__ float s_part[4 * WIN * WIN];
    const int lane = threadIdx.x & 63;
    const int wave = threadIdx.x >> 6;
    #pragma unroll
    for (int c = 0; c < WIN * WIN; ++c) {
        float v = acc[c];
        #pragma unroll
        for (int off = 32; off > 0; off >>= 1) v += __shfl_down(v, off, 64);
        if (lane == 0) s_part[wave * (WIN * WIN) + c] = v;
    }
    __syncthreads();
    if (threadIdx.x < WIN * WIN) {
        float s = s_part[threadIdx.x] + s_part[49 + threadIdx.x]
                + s_part[98 + threadIdx.x] + s_part[147 + threadIdx.x];
        int cell = (ia + threadIdx.x / WIN) * NBINS + (ib + threadIdx.x % WIN);
        atomicAdd(&pab[b * NCELLS + cell], s);
    }
}

// ---------------- K3: fp64 finalize ----------------
__global__ __launch_bounds__(256)
void mi_finalize(const float* __restrict__ pab_in, float* __restrict__ out)
{
    __shared__ double s_pab[NCELLS];
    __shared__ double s_pa[NBINS];
    __shared__ double s_pb[NBINS];
    __shared__ double s_red[4];

    double total = 0.0;
    for (int b = 0; b < NBATCH; ++b) {
        for (int c = threadIdx.x; c < NCELLS; c += 256)
            s_pab[c] = (double)pab_in[b * NCELLS + c] * (1.0 / (double)NVOX);
        __syncthreads();
        if (threadIdx.x < NBINS) {
            const int i = threadIdx.x;
            double r = 0.0, cl = 0.0;
            for (int j = 0; j < NBINS; ++j) {
                r  += s_pab[i * NBINS + j];
                cl += s_pab[j * NBINS + i];
            }
            s_pa[i] = r; s_pb[i] = cl;
        }
        __syncthreads();
        double t = 0.0;
        for (int c = threadIdx.x; c < NCELLS; c += 256) {
            double pv   = s_pab[c];
            double papb = s_pa[c / NBINS] * s_pb[c % NBINS];
            t += pv * log((pv + 1e-7) / (papb + 1e-7) + 1e-7);
        }
        #pragma unroll
        for (int off = 32; off > 0; off >>= 1) t += __shfl_down(t, off, 64);
        if ((threadIdx.x & 63) == 0) s_red[threadIdx.x >> 6] = t;
        __syncthreads();
        if (threadIdx.x == 0) total += s_red[0] + s_red[1] + s_red[2] + s_red[3];
        __syncthreads();
    }
    if (threadIdx.x == 0) out[0] = (float)(-total * 0.25);
}

// ---------------- Round-1 fallback kernels (small-ws insurance) ----------------
__global__ __launch_bounds__(256)
void mi_pab_partial_r1(const float* __restrict__ pred,
                       const float* __restrict__ targ,
                       float* __restrict__ partial)
{
    __shared__ float s_pab[NCELLS];
    const int chunk = blockIdx.x;
    const int b     = blockIdx.y;
    for (int c = threadIdx.x; c < NCELLS; c += 256) s_pab[c] = 0.0f;
    __syncthreads();
    const float* px = pred + (size_t)b * NVOX + (size_t)chunk * R1VPC;
    const float* py = targ + (size_t)b * NVOX + (size_t)chunk * R1VPC;
    for (int v = threadIdx.x; v < R1VPC; v += 256) {
        float x = px[v]; x = fminf(fmaxf(x, 0.0f), 1.0f);
        float y = py[v]; y = fminf(fmaxf(y, 0.0f), 1.0f);
        int ka = (int)floorf(fmaf(x, 22.0f, 0.5f));
        int kb = (int)floorf(fmaf(y, 22.0f, 0.5f));
        int ia = ka - 3; ia = ia < 0 ? 0 : (ia > 16 ? 16 : ia);
        int ib = kb - 3; ib = ib < 0 ? 0 : (ib > 16 ? 16 : ib);
        float wa[WIN], wb[WIN], sa, sb;
        window_weights(x, ia, wa, sa);
        window_weights(y, ib, wb, sb);
        float scale = 1.0f / (sa * sb);
        #pragma unroll
        for (int ta = 0; ta < WIN; ++ta) {
            float fa = wa[ta] * scale;
            int rb = (ia + ta) * NBINS + ib;
            #pragma unroll
            for (int tb = 0; tb < WIN; ++tb)
                atomicAdd(&s_pab[rb + tb], fa * wb[tb]);
        }
    }
    __syncthreads();
    for (int c = threadIdx.x; c < NCELLS; c += 256)
        partial[((size_t)b * NCELLS + c) * R1CHUNKS + chunk] = s_pab[c];
}

__global__ __launch_bounds__(256)
void mi_finalize_r1(const float* __restrict__ partial, float* __restrict__ out)
{
    __shared__ double s_pab[NCELLS];
    __shared__ double s_pa[NBINS];
    __shared__ double s_pb[NBINS];
    __shared__ double s_red[4];
    double total = 0.0;
    for (int b = 0; b < NBATCH; ++b) {
        for (int c = threadIdx.x; c < NCELLS; c += 256) {
            const float4* p = (const float4*)(partial + ((size_t)b * NCELLS + c) * R1CHUNKS);
            double s = 0.0;
            #pragma unroll 4
            for (int k = 0; k < R1CHUNKS / 4; ++k) {
                float4 q = p[k];
                s += (double)q.x + (double)q.y + (double)q.z + (double)q.w;
            }
            s_pab[c] = s * (1.0 / (double)NVOX);
        }
        __syncthreads();
        if (threadIdx.x < NBINS) {
            const int i = threadIdx.x;
            double r = 0.0, cl = 0.0;
            for (int j = 0; j < NBINS; ++j) {
                r  += s_pab[i * NBINS + j];
                cl += s_pab[j * NBINS + i];
            }
            s_pa[i] = r; s_pb[i] = cl;
        }
        __syncthreads();
        double t = 0.0;
        for (int c = threadIdx.x; c < NCELLS; c += 256) {
            double pv   = s_pab[c];
            double papb = s_pa[c / NBINS] * s_pb[c % NBINS];
            t += pv * log((pv + 1e-7) / (papb + 1e-7) + 1e-7);
        }
        #pragma unroll
        for (int off = 32; off > 0; off >>= 1) t += __shfl_down(t, off, 64);
        if ((threadIdx.x & 63) == 0) s_red[threadIdx.x >> 6] = t;
        __syncthreads();
        if (threadIdx.x == 0) total += s_red[0] + s_red[1] + s_red[2] + s_red[3];
        __syncthreads();
    }
    if (threadIdx.x == 0) out[0] = (float)(-total * 0.25);
}

extern "C" void kernel_launch(void* const* d_in, const int* in_sizes, int n_in,
                              void* d_out, int out_size, void* d_ws, size_t ws_size,
                              hipStream_t stream)
{
    const float* pred = (const float*)d_in[0];
    const float* targ = (const float*)d_in[1];
    float* out = (float*)d_out;
    char* ws = (char*)d_ws;

    // layout: [cnt: NBUCK u32][pad][pab: NBUCK f32][pad][buf: NBUCK*CAP float2]
    const size_t off_cnt = 0;
    const size_t off_pab = 8704;           // >= NBUCK*4 = 8464
    const size_t off_buf = 17408;
    const size_t needed  = off_buf + (size_t)NBUCK * CAP * sizeof(float2); // ~34.7 MB

    if (ws_size >= needed) {
        unsigned int* cnt = (unsigned int*)(ws + off_cnt);
        float* pab        = (float*)(ws + off_pab);
        float2* buf       = (float2*)(ws + off_buf);
        hipMemsetAsync(ws, 0, off_buf, stream);  // zero cnt + pab
        mi_scatter<<<dim3(SCHUNKS, NBATCH), 256, 0, stream>>>(pred, targ, cnt, buf, pab);
        mi_accum<<<NBUCK, 256, 0, stream>>>(cnt, buf, pab);
        mi_finalize<<<1, 256, 0, stream>>>(pab, out);
    } else {
        float* partial = (float*)ws;  // NBATCH*NCELLS*R1CHUNKS floats ~ 1.06 MB
        mi_pab_partial_r1<<<dim3(R1CHUNKS, NBATCH), 256, 0, stream>>>(pred, targ, partial);
        mi_finalize_r1<<<1, 256, 0, stream>>>(partial, out);
    }
}

// Round 4
// 303.833 us; speedup vs baseline: 3.2070x; 2.0380x over previous
//
#include <hip/hip_runtime.h>
#include <math.h>

// MutualInformationLoss on MI355X — round 3b (compile fix of round 3).
// Round-2 bottleneck: mi_scatter 508 us — hot-address device atomics (~278 cyc
// x 1828 on the hottest bucket) + cross-XCD L2 line churn (WRITE_SIZE 160 MB
// for a 28 MB payload). Fix: 8 replica segments per bucket keyed by
// blockIdx.x&7 (== XCD under round-robin dispatch, gridDim.x % 8 == 0):
// 8x less per-address serialization AND XCD-local segment writes.
// r3b: __builtin_nontemporal_load needs a native vector type, not
// HIP_vector_type<float,4> — use ext_vector_type(4) float.

#define NBINS   23
#define NCELLS  529
#define NBATCH  4
#define NVOX    884736
#define NBUCK   (NBATCH * NCELLS)     // 2116
#define NREP    8
#define CAPR    252                   // per-replica segment capacity
#define CAP     (NREP * CAPR)         // 2016 per bucket (max expected ~1970)
#define WIN     7
#define SVPC    2048                  // voxels per scatter block
#define SCHUNKS (NVOX / SVPC)         // 432 (divisible by 8)

#define R1CHUNKS 128
#define R1VPC    (NVOX / R1CHUNKS)

typedef float vfloat4 __attribute__((ext_vector_type(4)));

__device__ __forceinline__ void window_weights(float x, int ia, float* w, float& s)
{
    const float BINW = (float)(1.0 / 22.0);
    const float PT   = 968.0f;
    s = 0.0f;
    #pragma unroll
    for (int t = 0; t < WIN; ++t) {
        float d = x - (float)(ia + t) * BINW;
        float wv = expf(-PT * d * d);
        w[t] = wv; s += wv;
    }
}

__device__ __forceinline__ void direct_contrib(float x, float y, int b, float* pab)
{
    int ka = (int)floorf(fmaf(x, 22.0f, 0.5f));
    int kb = (int)floorf(fmaf(y, 22.0f, 0.5f));
    int ia = ka - 3; ia = ia < 0 ? 0 : (ia > 16 ? 16 : ia);
    int ib = kb - 3; ib = ib < 0 ? 0 : (ib > 16 ? 16 : ib);
    float wa[WIN], wb[WIN], sa, sb;
    window_weights(x, ia, wa, sa);
    window_weights(y, ib, wb, sb);
    float scale = 1.0f / (sa * sb);
    #pragma unroll
    for (int ta = 0; ta < WIN; ++ta) {
        float fa = wa[ta] * scale;
        #pragma unroll
        for (int tb = 0; tb < WIN; ++tb)
            atomicAdd(&pab[b * NCELLS + (ia + ta) * NBINS + (ib + tb)], fa * wb[tb]);
    }
}

// ---------------- K1: replica-partitioned scatter ----------------
__global__ __launch_bounds__(256)
void mi_scatter(const float* __restrict__ pred,
                const float* __restrict__ targ,
                unsigned int* __restrict__ cnt,     // [NREP][NBUCK]
                float2* __restrict__ buf,           // [NBUCK][NREP][CAPR]
                float* __restrict__ pab)            // overflow fallback target
{
    const int chunk = blockIdx.x;
    const int b     = blockIdx.y;
    const int rep0  = blockIdx.x & 7;   // XCD-local under round-robin dispatch

    const vfloat4* __restrict__ px4 =
        (const vfloat4*)(pred + (size_t)b * NVOX + (size_t)chunk * SVPC);
    const vfloat4* __restrict__ py4 =
        (const vfloat4*)(targ + (size_t)b * NVOX + (size_t)chunk * SVPC);

    #pragma unroll
    for (int it = 0; it < SVPC / 1024; ++it) {
        const int v = it * 256 + threadIdx.x;
        vfloat4 X = __builtin_nontemporal_load(&px4[v]);
        vfloat4 Y = __builtin_nontemporal_load(&py4[v]);
        float xs[4] = {X.x, X.y, X.z, X.w};
        float ys[4] = {Y.x, Y.y, Y.z, Y.w};
        #pragma unroll
        for (int k = 0; k < 4; ++k) {
            float x = fminf(fmaxf(xs[k], 0.0f), 1.0f);
            float y = fminf(fmaxf(ys[k], 0.0f), 1.0f);
            int ka = (int)floorf(fmaf(x, 22.0f, 0.5f));
            int kb = (int)floorf(fmaf(y, 22.0f, 0.5f));
            int bucket = (b * NBINS + ka) * NBINS + kb;

            int rep = rep0;
            unsigned int pos = atomicAdd(&cnt[rep * NBUCK + bucket], 1u);
            int tries = 0;
            while (pos >= CAPR && tries < NREP - 1) {   // spill-chain (rare)
                rep = (rep + 1) & 7;
                pos = atomicAdd(&cnt[rep * NBUCK + bucket], 1u);
                ++tries;
            }
            if (pos < CAPR)
                buf[(size_t)bucket * CAP + rep * CAPR + pos] = make_float2(x, y);
            else
                direct_contrib(x, y, b, pab);           // capacity-proof fallback
        }
    }
}

// ---------------- K2: dense register accumulation per bucket ----------------
__global__ __launch_bounds__(256)
void mi_accum(const unsigned int* __restrict__ cnt,
              const float2* __restrict__ buf,
              float* __restrict__ pab)
{
    const int bucket = blockIdx.x;
    const int kb = bucket % NBINS;
    const int ka = (bucket / NBINS) % NBINS;
    const int b  = bucket / NCELLS;
    int ia = ka - 3; ia = ia < 0 ? 0 : (ia > 16 ? 16 : ia);
    int ib = kb - 3; ib = ib < 0 ? 0 : (ib > 16 ? 16 : ib);

    float acc[WIN * WIN];
    #pragma unroll
    for (int c = 0; c < WIN * WIN; ++c) acc[c] = 0.0f;

    #pragma unroll
    for (int r = 0; r < NREP; ++r) {
        unsigned int n = cnt[r * NBUCK + bucket];
        if (n > CAPR) n = CAPR;
        // CAPR <= 256: each thread handles at most one voxel per segment
        if (threadIdx.x < n) {
            float2 p = buf[(size_t)bucket * CAP + r * CAPR + threadIdx.x];
            float wa[WIN], wb[WIN], sa, sb;
            window_weights(p.x, ia, wa, sa);
            window_weights(p.y, ib, wb, sb);
            float scale = 1.0f / (sa * sb);
            #pragma unroll
            for (int ta = 0; ta < WIN; ++ta) {
                float fa = wa[ta] * scale;
                #pragma unroll
                for (int tb = 0; tb < WIN; ++tb)
                    acc[ta * WIN + tb] = fmaf(fa, wb[tb], acc[ta * WIN + tb]);
            }
        }
    }

    __shared__ float s_part[4 * WIN * WIN];
    const int lane = threadIdx.x & 63;
    const int wave = threadIdx.x >> 6;
    #pragma unroll
    for (int c = 0; c < WIN * WIN; ++c) {
        float v = acc[c];
        #pragma unroll
        for (int off = 32; off > 0; off >>= 1) v += __shfl_down(v, off, 64);
        if (lane == 0) s_part[wave * (WIN * WIN) + c] = v;
    }
    __syncthreads();
    if (threadIdx.x < WIN * WIN) {
        float s = s_part[threadIdx.x] + s_part[49 + threadIdx.x]
                + s_part[98 + threadIdx.x] + s_part[147 + threadIdx.x];
        int cell = (ia + threadIdx.x / WIN) * NBINS + (ib + threadIdx.x % WIN);
        atomicAdd(&pab[b * NCELLS + cell], s);
    }
}

// ---------------- K3: fp64 finalize ----------------
__global__ __launch_bounds__(256)
void mi_finalize(const float* __restrict__ pab_in, float* __restrict__ out)
{
    __shared__ double s_pab[NCELLS];
    __shared__ double s_pa[NBINS];
    __shared__ double s_pb[NBINS];
    __shared__ double s_red[4];

    double total = 0.0;
    for (int b = 0; b < NBATCH; ++b) {
        for (int c = threadIdx.x; c < NCELLS; c += 256)
            s_pab[c] = (double)pab_in[b * NCELLS + c] * (1.0 / (double)NVOX);
        __syncthreads();
        if (threadIdx.x < NBINS) {
            const int i = threadIdx.x;
            double r = 0.0, cl = 0.0;
            for (int j = 0; j < NBINS; ++j) {
                r  += s_pab[i * NBINS + j];
                cl += s_pab[j * NBINS + i];
            }
            s_pa[i] = r; s_pb[i] = cl;
        }
        __syncthreads();
        double t = 0.0;
        for (int c = threadIdx.x; c < NCELLS; c += 256) {
            double pv   = s_pab[c];
            double papb = s_pa[c / NBINS] * s_pb[c % NBINS];
            t += pv * log((pv + 1e-7) / (papb + 1e-7) + 1e-7);
        }
        #pragma unroll
        for (int off = 32; off > 0; off >>= 1) t += __shfl_down(t, off, 64);
        if ((threadIdx.x & 63) == 0) s_red[threadIdx.x >> 6] = t;
        __syncthreads();
        if (threadIdx.x == 0) total += s_red[0] + s_red[1] + s_red[2] + s_red[3];
        __syncthreads();
    }
    if (threadIdx.x == 0) out[0] = (float)(-total * 0.25);
}

// ---------------- Round-1 fallback kernels (small-ws insurance) ----------------
__global__ __launch_bounds__(256)
void mi_pab_partial_r1(const float* __restrict__ pred,
                       const float* __restrict__ targ,
                       float* __restrict__ partial)
{
    __shared__ float s_pab[NCELLS];
    const int chunk = blockIdx.x;
    const int b     = blockIdx.y;
    for (int c = threadIdx.x; c < NCELLS; c += 256) s_pab[c] = 0.0f;
    __syncthreads();
    const float* px = pred + (size_t)b * NVOX + (size_t)chunk * R1VPC;
    const float* py = targ + (size_t)b * NVOX + (size_t)chunk * R1VPC;
    for (int v = threadIdx.x; v < R1VPC; v += 256) {
        float x = px[v]; x = fminf(fmaxf(x, 0.0f), 1.0f);
        float y = py[v]; y = fminf(fmaxf(y, 0.0f), 1.0f);
        int ka = (int)floorf(fmaf(x, 22.0f, 0.5f));
        int kb = (int)floorf(fmaf(y, 22.0f, 0.5f));
        int ia = ka - 3; ia = ia < 0 ? 0 : (ia > 16 ? 16 : ia);
        int ib = kb - 3; ib = ib < 0 ? 0 : (ib > 16 ? 16 : ib);
        float wa[WIN], wb[WIN], sa, sb;
        window_weights(x, ia, wa, sa);
        window_weights(y, ib, wb, sb);
        float scale = 1.0f / (sa * sb);
        #pragma unroll
        for (int ta = 0; ta < WIN; ++ta) {
            float fa = wa[ta] * scale;
            int rb = (ia + ta) * NBINS + ib;
            #pragma unroll
            for (int tb = 0; tb < WIN; ++tb)
                atomicAdd(&s_pab[rb + tb], fa * wb[tb]);
        }
    }
    __syncthreads();
    for (int c = threadIdx.x; c < NCELLS; c += 256)
        partial[((size_t)b * NCELLS + c) * R1CHUNKS + chunk] = s_pab[c];
}

__global__ __launch_bounds__(256)
void mi_finalize_r1(const float* __restrict__ partial, float* __restrict__ out)
{
    __shared__ double s_pab[NCELLS];
    __shared__ double s_pa[NBINS];
    __shared__ double s_pb[NBINS];
    __shared__ double s_red[4];
    double total = 0.0;
    for (int b = 0; b < NBATCH; ++b) {
        for (int c = threadIdx.x; c < NCELLS; c += 256) {
            const float4* p = (const float4*)(partial + ((size_t)b * NCELLS + c) * R1CHUNKS);
            double s = 0.0;
            #pragma unroll 4
            for (int k = 0; k < R1CHUNKS / 4; ++k) {
                float4 q = p[k];
                s += (double)q.x + (double)q.y + (double)q.z + (double)q.w;
            }
            s_pab[c] = s * (1.0 / (double)NVOX);
        }
        __syncthreads();
        if (threadIdx.x < NBINS) {
            const int i = threadIdx.x;
            double r = 0.0, cl = 0.0;
            for (int j = 0; j < NBINS; ++j) {
                r  += s_pab[i * NBINS + j];
                cl += s_pab[j * NBINS + i];
            }
            s_pa[i] = r; s_pb[i] = cl;
        }
        __syncthreads();
        double t = 0.0;
        for (int c = threadIdx.x; c < 529; c += 256) {
            double pv   = s_pab[c];
            double papb = s_pa[c / NBINS] * s_pb[c % NBINS];
            t += pv * log((pv + 1e-7) / (papb + 1e-7) + 1e-7);
        }
        #pragma unroll
        for (int off = 32; off > 0; off >>= 1) t += __shfl_down(t, off, 64);
        if ((threadIdx.x & 63) == 0) s_red[threadIdx.x >> 6] = t;
        __syncthreads();
        if (threadIdx.x == 0) total += s_red[0] + s_red[1] + s_red[2] + s_red[3];
        __syncthreads();
    }
    if (threadIdx.x == 0) out[0] = (float)(-total * 0.25);
}

extern "C" void kernel_launch(void* const* d_in, const int* in_sizes, int n_in,
                              void* d_out, int out_size, void* d_ws, size_t ws_size,
                              hipStream_t stream)
{
    const float* pred = (const float*)d_in[0];
    const float* targ = (const float*)d_in[1];
    float* out = (float*)d_out;
    char* ws = (char*)d_ws;

    // layout: [cnt: NREP*NBUCK u32 = 67712 B][pab: NBUCK f32 = 8464 B][buf]
    const size_t off_cnt = 0;
    const size_t off_pab = 67712;
    const size_t off_buf = 76176;
    const size_t needed  = off_buf + (size_t)NBUCK * CAP * sizeof(float2); // ~34.2 MB

    if (ws_size >= needed) {
        unsigned int* cnt = (unsigned int*)(ws + off_cnt);
        float* pab        = (float*)(ws + off_pab);
        float2* buf       = (float2*)(ws + off_buf);
        (void)hipMemsetAsync(ws, 0, off_buf, stream);  // zero cnt + pab
        mi_scatter<<<dim3(SCHUNKS, NBATCH), 256, 0, stream>>>(pred, targ, cnt, buf, pab);
        mi_accum<<<NBUCK, 256, 0, stream>>>(cnt, buf, pab);
        mi_finalize<<<1, 256, 0, stream>>>(pab, out);
    } else {
        float* partial = (float*)ws;  // ~1.06 MB
        mi_pab_partial_r1<<<dim3(R1CHUNKS, NBATCH), 256, 0, stream>>>(pred, targ, partial);
        mi_finalize_r1<<<1, 256, 0, stream>>>(partial, out);
    }
}

// Round 5
// 189.017 us; speedup vs baseline: 5.1551x; 1.6074x over previous
//
#include <hip/hip_runtime.h>
#include <math.h>

// MutualInformationLoss on MI355X — round 5: MFMA reformulation.
// pab[b] = Wa^T * Wb  ([23,N]x[N,23] GEMM). Each wave builds dense Parzen
// rows in registers (2 bins/lane x 8 voxels/lane) and accumulates a 2x2 grid
// of 16x16x32 f16 MFMA tiles. Normalization 1/(sa*sb) folded onto A side;
// sa/sb via 16-lane quad butterfly. No atomics anywhere. fp16 cvt is RNE
// (scalar v_cvt_f16_f32) — RTZ pack would bias MI by ~5e-4.

#define NBINS   23
#define NCELLS  529
#define NBATCH  4
#define NVOX    884736
#define PBLK    216              // blocks per batch; 884736/216 = 4096
#define VPW     1024             // voxels per wave (4 waves/block)
#define NCHUNK  (VPW / 32)       // 32-voxel K-chunks per wave

typedef float    vf4 __attribute__((ext_vector_type(4)));
typedef float    f4  __attribute__((ext_vector_type(4)));
typedef _Float16 h8  __attribute__((ext_vector_type(8)));

// ---------------- K1: fused Parzen + MFMA joint histogram ----------------
__global__ __launch_bounds__(256)
void mi_mfma(const float* __restrict__ pred,
             const float* __restrict__ targ,
             float* __restrict__ partial)      // [NBATCH*NCELLS][PBLK]
{
    __shared__ float s_tile[4][32][34];        // per-wave C tiles (pad 34)

    const int p    = blockIdx.x;
    const int b    = blockIdx.y;
    const int wv   = threadIdx.x >> 6;
    const int lane = threadIdx.x & 63;
    const int q    = lane >> 4;                // quad: which 8-voxel group
    const int m    = lane & 15;                // bin (tile-local)

    const float c_lo = (float)m * (1.0f / 22.0f);
    const float c_hi = (float)(m + 16) * (1.0f / 22.0f);
    const bool  hiv  = (m + 16) < NBINS;       // bins 16..22 valid

    const size_t base = (size_t)b * NVOX + (size_t)p * (4 * VPW) + (size_t)wv * VPW;
    const vf4* __restrict__ px4 = (const vf4*)(pred + base);
    const vf4* __restrict__ py4 = (const vf4*)(targ + base);

    f4 acc00 = {0.f,0.f,0.f,0.f}, acc01 = {0.f,0.f,0.f,0.f};
    f4 acc10 = {0.f,0.f,0.f,0.f}, acc11 = {0.f,0.f,0.f,0.f};

    for (int c = 0; c < NCHUNK; ++c) {
        // quad q's 8 voxels of this 32-voxel K-chunk (broadcast within quad)
        vf4 xa = px4[c * 8 + q * 2], xb = px4[c * 8 + q * 2 + 1];
        vf4 ya = py4[c * 8 + q * 2], yb = py4[c * 8 + q * 2 + 1];
        float xs[8] = {xa.x, xa.y, xa.z, xa.w, xb.x, xb.y, xb.z, xb.w};
        float ys[8] = {ya.x, ya.y, ya.z, ya.w, yb.x, yb.y, yb.z, yb.w};

        float alo[8], ahi[8], blo[8], bhi[8], sa[8], sb[8];
        #pragma unroll
        for (int j = 0; j < 8; ++j) {
            float x = fminf(fmaxf(xs[j], 0.0f), 1.0f);
            float y = fminf(fmaxf(ys[j], 0.0f), 1.0f);
            float t0 = x - c_lo; alo[j] = __expf(-968.0f * t0 * t0);
            float t1 = x - c_hi; float eh = __expf(-968.0f * t1 * t1);
            ahi[j] = hiv ? eh : 0.0f;
            float u0 = y - c_lo; blo[j] = __expf(-968.0f * u0 * u0);
            float u1 = y - c_hi; float fh = __expf(-968.0f * u1 * u1);
            bhi[j] = hiv ? fh : 0.0f;
            sa[j] = alo[j] + ahi[j];
            sb[j] = blo[j] + bhi[j];
        }
        // per-voxel sums over 23 bins: butterfly across the 16-lane quad
        #pragma unroll
        for (int s = 1; s < 16; s <<= 1) {
            #pragma unroll
            for (int j = 0; j < 8; ++j) {
                sa[j] += __shfl_xor(sa[j], s, 16);
                sb[j] += __shfl_xor(sb[j], s, 16);
            }
        }
        h8 Alo, Ahi, Blo, Bhi;
        #pragma unroll
        for (int j = 0; j < 8; ++j) {
            float inv = __builtin_amdgcn_rcpf(sa[j] * sb[j]);  // 1 ulp, random sign
            Alo[j] = (_Float16)(alo[j] * inv);   // RNE cvt — do NOT use pkrtz
            Ahi[j] = (_Float16)(ahi[j] * inv);
            Blo[j] = (_Float16)blo[j];
            Bhi[j] = (_Float16)bhi[j];
        }
        acc00 = __builtin_amdgcn_mfma_f32_16x16x32_f16(Alo, Blo, acc00, 0, 0, 0);
        acc01 = __builtin_amdgcn_mfma_f32_16x16x32_f16(Alo, Bhi, acc01, 0, 0, 0);
        acc10 = __builtin_amdgcn_mfma_f32_16x16x32_f16(Ahi, Blo, acc10, 0, 0, 0);
        acc11 = __builtin_amdgcn_mfma_f32_16x16x32_f16(Ahi, Bhi, acc11, 0, 0, 0);
    }

    // C layout: col = lane&15, row = quad*4 + reg  (verified m89/m91)
    #pragma unroll
    for (int r = 0; r < 4; ++r) {
        s_tile[wv][q * 4 + r     ][m     ] = acc00[r];
        s_tile[wv][q * 4 + r     ][16 + m] = acc01[r];
        s_tile[wv][16 + q * 4 + r][m     ] = acc10[r];
        s_tile[wv][16 + q * 4 + r][16 + m] = acc11[r];
    }
    __syncthreads();
    for (int c = threadIdx.x; c < NCELLS; c += 256) {
        int i = c / NBINS, j = c % NBINS;
        float s = s_tile[0][i][j] + s_tile[1][i][j]
                + s_tile[2][i][j] + s_tile[3][i][j];
        partial[((size_t)(b * NCELLS + c)) * PBLK + p] = s;
    }
}

// ---------------- K2: fp64 cross-block reduction per cell ----------------
__global__ __launch_bounds__(64)
void mi_reduce(const float* __restrict__ partial, double* __restrict__ pab64)
{
    const int c = blockIdx.x, b = blockIdx.y;
    const float* __restrict__ src = partial + ((size_t)(b * NCELLS + c)) * PBLK;
    double s = 0.0;
    for (int t = threadIdx.x; t < PBLK; t += 64) s += (double)src[t];
    #pragma unroll
    for (int off = 32; off > 0; off >>= 1) s += __shfl_down(s, off, 64);
    if (threadIdx.x == 0) pab64[b * NCELLS + c] = s * (1.0 / (double)NVOX);
}

// ---------------- K3: fp64 marginals + MI ----------------
__global__ __launch_bounds__(256)
void mi_final(const double* __restrict__ pab64, float* __restrict__ out)
{
    __shared__ double s_pab[NCELLS];
    __shared__ double s_pa[NBINS];
    __shared__ double s_pb[NBINS];
    __shared__ double s_red[4];

    double total = 0.0;
    for (int b = 0; b < NBATCH; ++b) {
        for (int c = threadIdx.x; c < NCELLS; c += 256)
            s_pab[c] = pab64[b * NCELLS + c];
        __syncthreads();
        if (threadIdx.x < NBINS) {
            const int i = threadIdx.x;
            double r = 0.0, cl = 0.0;
            for (int j = 0; j < NBINS; ++j) {
                r  += s_pab[i * NBINS + j];
                cl += s_pab[j * NBINS + i];
            }
            s_pa[i] = r; s_pb[i] = cl;
        }
        __syncthreads();
        double t = 0.0;
        for (int c = threadIdx.x; c < NCELLS; c += 256) {
            double pv   = s_pab[c];
            double papb = s_pa[c / NBINS] * s_pb[c % NBINS];
            t += pv * log((pv + 1e-7) / (papb + 1e-7) + 1e-7);
        }
        #pragma unroll
        for (int off = 32; off > 0; off >>= 1) t += __shfl_down(t, off, 64);
        if ((threadIdx.x & 63) == 0) s_red[threadIdx.x >> 6] = t;
        __syncthreads();
        if (threadIdx.x == 0) total += s_red[0] + s_red[1] + s_red[2] + s_red[3];
        __syncthreads();
    }
    if (threadIdx.x == 0) out[0] = (float)(-total * 0.25);
}

extern "C" void kernel_launch(void* const* d_in, const int* in_sizes, int n_in,
                              void* d_out, int out_size, void* d_ws, size_t ws_size,
                              hipStream_t stream)
{
    const float* pred = (const float*)d_in[0];
    const float* targ = (const float*)d_in[1];
    float* out = (float*)d_out;
    char* ws = (char*)d_ws;

    // layout: [partial: NBATCH*NCELLS*PBLK f32 = 1.83 MB][pab64: 2116 f64]
    const size_t off_partial = 0;
    const size_t off_pab64   = ((size_t)NBATCH * NCELLS * PBLK * 4 + 255) & ~(size_t)255;

    float*  partial = (float*)(ws + off_partial);
    double* pab64   = (double*)(ws + off_pab64);

    // every slot of partial/pab64 is fully written each call — no memset needed
    mi_mfma  <<<dim3(PBLK,  NBATCH), 256, 0, stream>>>(pred, targ, partial);
    mi_reduce<<<dim3(NCELLS, NBATCH), 64, 0, stream>>>(partial, pab64);
    mi_final <<<1, 256, 0, stream>>>(pab64, out);
}

// Round 6
// 109.249 us; speedup vs baseline: 8.9191x; 1.7302x over previous
//
#include <hip/hip_runtime.h>
#include <math.h>

// MutualInformationLoss on MI355X — round 6: sparse-window + LDS-image MFMA.
// Round-5 waste: 64 exps/voxel (dense bins in regs) + 64-shfl butterfly/chunk.
// Now: 1 voxel/lane/chunk, 7-bin window via factored Gaussian (3 trans/side):
//   w(t) = W0 * R^t * G(t),  W0=exp(-968 v^2), R=exp(88 v), G(t)=exp(-2 t^2),
//   v = x - (ia+3)/22, |88v| <= 14 so R^3 in fp32 range.
// Scatter 7 fp16/side into per-wave LDS images [bin][voxel] (stride 144 B),
// then 4x mfma_f32_32x32x16_f16 per 64-voxel chunk (32x32 covers all 23 bins).
// Rows 23..31 never zeroed: garbage only reaches C rows/cols >= 23 (unread).
// No barriers in the hot loop (per-wave LDS regions). fp16 cvt RNE (no pkrtz).

#define NBINS   23
#define NCELLS  529
#define NBATCH  4
#define NVOX    884736
#define PBLK    432               // blocks per batch: 432 * 2048 = 884736
#define RS      72                // image row stride in halves (144 B, 16B-mult)
#define IMGB    (32 * RS * 2)     // 4608 B per image (32 rows)
#define WREG    (2 * IMGB)        // 9216 B per wave (A + B images)

typedef float    vf4  __attribute__((ext_vector_type(4)));
typedef _Float16 h8   __attribute__((ext_vector_type(8)));
typedef float    f16v __attribute__((ext_vector_type(16)));

#define G1 0.13533528f        // exp(-2)
#define G2 3.3546263e-4f      // exp(-8)
#define G3 1.5229979e-8f      // exp(-18)

// 7-bin window at rows i0..i0+6, returns unnormalized sum; w[t] = Parzen weight
__device__ __forceinline__ float window7(float x, int& i0, float* w)
{
    x = fminf(fmaxf(x, 0.0f), 1.0f);
    int ka = (int)floorf(fmaf(x, 22.0f, 0.5f));
    i0 = min(max(ka - 3, 0), 16);
    float v  = fmaf((float)(i0 + 3), -(1.0f / 22.0f), x);  // x - center of mid bin
    float W0 = __expf(-968.0f * v * v);
    float R  = __expf(88.0f * v);
    float Ri = __builtin_amdgcn_rcpf(R);
    float R2 = R * R,   R3 = R2 * R;
    float R2i = Ri * Ri, R3i = R2i * Ri;
    w[0] = W0 * (R3i * G3);
    w[1] = W0 * (R2i * G2);
    w[2] = W0 * (Ri  * G1);
    w[3] = W0;
    w[4] = W0 * (R   * G1);
    w[5] = W0 * (R2  * G2);
    w[6] = W0 * (R3  * G3);
    return ((w[0] + w[6]) + (w[1] + w[5])) + ((w[2] + w[4]) + w[3]);
}

// ---------------- K1: fused Parzen-window + MFMA joint histogram ----------------
__global__ __launch_bounds__(256)
void mi_mfma(const float* __restrict__ pred,
             const float* __restrict__ targ,
             float* __restrict__ partial)      // [NBATCH*PBLK][NCELLS]
{
    __shared__ __align__(16) char smem[4 * WREG];   // 36864 B -> 4 blocks/CU

    const int p    = blockIdx.x;
    const int b    = blockIdx.y;
    const int wv   = threadIdx.x >> 6;
    const int lane = threadIdx.x & 63;
    const int m    = lane & 31;               // bin row for fragment reads
    const int h    = lane >> 5;               // k-half selector

    char* wbase = smem + wv * WREG;
    _Float16* Aimg = (_Float16*)wbase;
    _Float16* Bimg = (_Float16*)(wbase + IMGB);

    // lane's 8 voxels are contiguous: chunk c uses element c
    const size_t base = (size_t)b * NVOX + (size_t)p * 2048 + (size_t)wv * 512
                      + (size_t)lane * 8;
    const vf4* __restrict__ px4 = (const vf4*)(pred + base);
    const vf4* __restrict__ py4 = (const vf4*)(targ + base);
    vf4 xa = px4[0], xb = px4[1], ya = py4[0], yb = py4[1];
    float xs[8] = {xa.x, xa.y, xa.z, xa.w, xb.x, xb.y, xb.z, xb.w};
    float ys[8] = {ya.x, ya.y, ya.z, ya.w, yb.x, yb.y, yb.z, yb.w};

    f16v acc = {};

    #pragma unroll
    for (int c = 0; c < 8; ++c) {
        // zero rows 0..22 of both images (4096 B each; overshoot into the
        // don't-care zone rows 23..28 is harmless, stays inside the image)
        vf4 z = {0.f, 0.f, 0.f, 0.f};
        #pragma unroll
        for (int it = 0; it < 4; ++it) {
            *(vf4*)(wbase        + (it * 64 + lane) * 16) = z;
            *(vf4*)(wbase + IMGB + (it * 64 + lane) * 16) = z;
        }

        int ia, ja;
        float wa[7], wb[7];
        float sa = window7(xs[c], ia, wa);
        float sb = window7(ys[c], ja, wb);
        float inv = __builtin_amdgcn_rcpf(sa * sb);   // fold both norms onto A

        #pragma unroll
        for (int t = 0; t < 7; ++t) {
            Aimg[(ia + t) * RS + lane] = (_Float16)(wa[t] * inv);  // RNE cvt
            Bimg[(ja + t) * RS + lane] = (_Float16)wb[t];
        }

        // fragment reads + 4 k-steps of 32x32x16 (K=16 voxels each)
        #pragma unroll
        for (int s = 0; s < 4; ++s) {
            h8 Af = *(const h8*)(Aimg + m * RS + 16 * s + 8 * h);
            h8 Bf = *(const h8*)(Bimg + m * RS + 16 * s + 8 * h);
            acc = __builtin_amdgcn_mfma_f32_32x32x16_f16(Af, Bf, acc, 0, 0, 0);
        }
    }

    // epilogue: C layout col=lane&31, row=(reg&3)+8*(reg>>2)+4*h (m74/m101)
    float* tile = (float*)wbase;               // reuse wave region (4224 B)
    #pragma unroll
    for (int r = 0; r < 16; ++r) {
        int row = (r & 3) + 8 * (r >> 2) + 4 * h;
        tile[row * 33 + m] = acc[r];
    }
    __syncthreads();
    for (int c = threadIdx.x; c < NCELLS; c += 256) {
        int i = c / NBINS, j = c % NBINS;
        float s = 0.0f;
        #pragma unroll
        for (int w = 0; w < 4; ++w)
            s += ((const float*)(smem + w * WREG))[i * 33 + j];
        partial[((size_t)(b * PBLK + p)) * NCELLS + c] = s;   // coalesced rows
    }
}

// ---------------- K2: fp64 cross-block reduction per cell ----------------
__global__ __launch_bounds__(64)
void mi_reduce(const float* __restrict__ partial, double* __restrict__ pab64)
{
    const int c = blockIdx.x, b = blockIdx.y;
    double s = 0.0;
    for (int t = threadIdx.x; t < PBLK; t += 64)
        s += (double)partial[((size_t)(b * PBLK + t)) * NCELLS + c];
    #pragma unroll
    for (int off = 32; off > 0; off >>= 1) s += __shfl_down(s, off, 64);
    if (threadIdx.x == 0) pab64[b * NCELLS + c] = s * (1.0 / (double)NVOX);
}

// ---------------- K3: fp64 marginals + MI ----------------
__global__ __launch_bounds__(256)
void mi_final(const double* __restrict__ pab64, float* __restrict__ out)
{
    __shared__ double s_pab[NCELLS];
    __shared__ double s_pa[NBINS];
    __shared__ double s_pb[NBINS];
    __shared__ double s_red[4];

    double total = 0.0;
    for (int b = 0; b < NBATCH; ++b) {
        for (int c = threadIdx.x; c < NCELLS; c += 256)
            s_pab[c] = pab64[b * NCELLS + c];
        __syncthreads();
        if (threadIdx.x < NBINS) {
            const int i = threadIdx.x;
            double r = 0.0, cl = 0.0;
            for (int j = 0; j < NBINS; ++j) {
                r  += s_pab[i * NBINS + j];
                cl += s_pab[j * NBINS + i];
            }
            s_pa[i] = r; s_pb[i] = cl;
        }
        __syncthreads();
        double t = 0.0;
        for (int c = threadIdx.x; c < NCELLS; c += 256) {
            double pv   = s_pab[c];
            double papb = s_pa[c / NBINS] * s_pb[c % NBINS];
            t += pv * log((pv + 1e-7) / (papb + 1e-7) + 1e-7);
        }
        #pragma unroll
        for (int off = 32; off > 0; off >>= 1) t += __shfl_down(t, off, 64);
        if ((threadIdx.x & 63) == 0) s_red[threadIdx.x >> 6] = t;
        __syncthreads();
        if (threadIdx.x == 0) total += s_red[0] + s_red[1] + s_red[2] + s_red[3];
        __syncthreads();
    }
    if (threadIdx.x == 0) out[0] = (float)(-total * 0.25);
}

extern "C" void kernel_launch(void* const* d_in, const int* in_sizes, int n_in,
                              void* d_out, int out_size, void* d_ws, size_t ws_size,
                              hipStream_t stream)
{
    const float* pred = (const float*)d_in[0];
    const float* targ = (const float*)d_in[1];
    float* out = (float*)d_out;
    char* ws = (char*)d_ws;

    // layout: [partial: NBATCH*PBLK*NCELLS f32 = 3.66 MB][pab64: 2116 f64]
    const size_t off_partial = 0;
    const size_t off_pab64   =
        ((size_t)NBATCH * PBLK * NCELLS * 4 + 255) & ~(size_t)255;

    float*  partial = (float*)(ws + off_partial);
    double* pab64   = (double*)(ws + off_pab64);

    // every slot of partial/pab64 is fully written each call — no memset needed
    mi_mfma  <<<dim3(PBLK,   NBATCH), 256, 0, stream>>>(pred, targ, partial);
    mi_reduce<<<dim3(NCELLS, NBATCH),  64, 0, stream>>>(partial, pab64);
    mi_final <<<1, 256, 0, stream>>>(pab64, out);
}